// Round 7
// baseline (169.025 us; speedup 1.0000x reference)
//
#include <hip/hip_runtime.h>
#include <math.h>

// Problem constants (from reference)
#define BATCH   8192
#define MROWS   16384      // 2*BATCH rows processed through the MLP
#define DIN     512
#define DH      256
#define DOUT    128
#define EPS_BN  1e-5f
#define TEMP    0.07f

using f4    = __attribute__((ext_vector_type(4))) float;
using f32x4 = __attribute__((ext_vector_type(4))) float;
using h4    = __attribute__((ext_vector_type(4))) _Float16;
using h8    = __attribute__((ext_vector_type(8))) _Float16;

// async global->LDS, 16B per lane: per-lane GLOBAL src, wave-uniform LDS base
#define GLD_LDS16(gp, lp) __builtin_amdgcn_global_load_lds( \
    (const __attribute__((address_space(1))) void*)(gp),    \
    (__attribute__((address_space(3))) void*)(lp), 16, 0, 0)

#define VMCNT(n) asm volatile("s_waitcnt vmcnt(" #n ")" ::: "memory")
#define LGKM0()  asm volatile("s_waitcnt lgkmcnt(0)" ::: "memory")

// ---------------------------------------------------------------------------
// Fully-fused fp16x3 GEMM (round 7 = round 6 + depth-3 A-register pipeline):
//   C = f(A) @ B + bias,  f = identity (FUSE_BN=0) or BN-affine+ReLU (=1)
//   A@B via fp16 hi/lo split: Ahi.Bhi + Alo.Bhi + Ahi.Blo
// Schedule per k-tile t: stageB(t+2) -> compute(t) -> vmcnt(W) -> procA(t+1)
// -> loadA(t+4) -> lgkm0 -> barrier.  A regs ride >=2 full iterations (HBM
// latency covered); B (L2-resident W splits) rides 1 iteration.  Steady-state
// FIFO at vmcnt: A(t+2),B(t+1),A(t+3),B(t+2) -> drain thru B(t+1) leaves
// A(t+3)[2]+B(t+2)[4] = vmcnt(6); tails 4/0.  A(t+1) is always older than
// B(t) so the previous iteration's wait already drained it.
// Ring-3 LDS 74KB -> 2 blocks/CU.  BM=64 BN=128 BK=32, 4 waves (2x2),
// mfma_f32_16x16x32_f16 (frag maps HW-verified rounds 4-6).
// EPI=0: C + per-col BN stats.  EPI=1: rownorm + reps + Svec.
// Grid 1-D: by=wg&255, bx=wg>>8 -> col-pair same XCD (256%8==0), A hits L2.
// ---------------------------------------------------------------------------
template <int K, int N, int FUSE_BN, int EPI>
__global__ __launch_bounds__(256, 2) void gemm_fused(
    const float* __restrict__ A1, const float* __restrict__ A2, int splitRow,
    const _Float16* __restrict__ BThi, const _Float16* __restrict__ BTlo,
    const float* __restrict__ stats, const float* __restrict__ g,
    const float* __restrict__ beta, const float* __restrict__ bias,
    float* __restrict__ Cout, float* __restrict__ red)
{
    constexpr int NT = K / 32;               // 32-k tiles (16 / 8 / 8)

    const int tid = threadIdx.x;
    const int wave = tid >> 6, lane = tid & 63;
    const int wr = wave >> 1, wc = wave & 1;
    const int l4 = lane >> 4, lc = lane & 15;
    const int wg = blockIdx.x;
    const int brow = (wg & 255) * 64;
    const int bcol = (wg >> 8) * 128;
    const int half = (brow >= BATCH) ? 1 : 0;

    __shared__ __align__(16) char smem[75776];
    _Float16* Bring = (_Float16*)smem;             // [3][8192]: hi 8 frags, lo 8
    _Float16* Aring = (_Float16*)(smem + 49152);   // [3][4096]: hi 4 frags, lo 4
    float*    scsh  = (float*)(smem + 73728);      // sc[256], sh[256]
    float*    sR    = (float*)(smem + 49152);      // epilogue alias (8KB)
    float*    nLp   = (float*)(smem + 49152 + 8192);

    // ---- B staging: wave w handles frags {2w, 2w+1} of Bhi and Blo ----
    const _Float16* bsrc[4];
    {
        const int co = (bcol + wave * 32 + lc) * K + l4 * 8;
        bsrc[0] = BThi + co;
        bsrc[1] = BThi + co + 16 * K;
        bsrc[2] = BTlo + co;
        bsrc[3] = BTlo + co + 16 * K;
    }
    auto stageB = [&](int buf, int t) {
        _Float16* d = Bring + buf * 8192 + wave * 1024;
        GLD_LDS16(bsrc[0] + t * 32, d);
        GLD_LDS16(bsrc[1] + t * 32, d + 512);
        GLD_LDS16(bsrc[2] + t * 32, d + 4096);
        GLD_LDS16(bsrc[3] + t * 32, d + 4096 + 512);
    };

    // ---- A: wave w = frag w; lane l: row=w*16+(l&15), k0=(l>>4)*8 ----
    const int arow = wave * 16 + lc;
    const int ak0 = l4 * 8;
    const int growA = brow + arow;
    const float* asrc = (growA < splitRow)
        ? (A1 + (size_t)growA * K + ak0)
        : (A2 + (size_t)(growA - splitRow) * K + ak0);

    f4 ar[3][2];                             // 3-deep A register ring
    auto loadA = [&](int p, int t) {
        ar[p][0] = *(const f4*)(asrc + t * 32);
        ar[p][1] = *(const f4*)(asrc + t * 32 + 4);
    };
    auto procA = [&](int p, int buf, int t) {
        float v[8];
#pragma unroll
        for (int j = 0; j < 4; ++j) { v[j] = ar[p][0][j]; v[4 + j] = ar[p][1][j]; }
        if constexpr (FUSE_BN) {
            f4 s0 = *(const f4*)&scsh[t * 32 + ak0];
            f4 s1 = *(const f4*)&scsh[t * 32 + ak0 + 4];
            f4 h0 = *(const f4*)&scsh[256 + t * 32 + ak0];
            f4 h1 = *(const f4*)&scsh[256 + t * 32 + ak0 + 4];
#pragma unroll
            for (int j = 0; j < 4; ++j) {
                v[j]     = fmaxf(fmaf(v[j],     s0[j], h0[j]), 0.f);
                v[4 + j] = fmaxf(fmaf(v[4 + j], s1[j], h1[j]), 0.f);
            }
        }
        h8 hi, lo;
#pragma unroll
        for (int j = 0; j < 8; ++j) {
            _Float16 h = (_Float16)v[j];
            hi[j] = h;
            lo[j] = (_Float16)(v[j] - (float)h);
        }
        _Float16* d = Aring + buf * 4096 + wave * 512 + lane * 8;
        *(h8*)d = hi;
        *(h8*)(d + 2048) = lo;
    };

    f32x4 acc[2][4];
#pragma unroll
    for (int mi = 0; mi < 2; ++mi)
#pragma unroll
        for (int ni = 0; ni < 4; ++ni)
#pragma unroll
            for (int c = 0; c < 4; ++c) acc[mi][ni][c] = 0.f;

    auto compute = [&](int buf) {
        const _Float16* Ab = Aring + buf * 4096;
        const _Float16* Bb = Bring + buf * 8192;
        h8 ah[2], al[2], bh[4], bl[4];
#pragma unroll
        for (int mi = 0; mi < 2; ++mi) {
            ah[mi] = *(const h8*)(Ab + (wr * 2 + mi) * 512 + lane * 8);
            al[mi] = *(const h8*)(Ab + 2048 + (wr * 2 + mi) * 512 + lane * 8);
        }
#pragma unroll
        for (int ni = 0; ni < 4; ++ni) {
            bh[ni] = *(const h8*)(Bb + (wc * 4 + ni) * 512 + lane * 8);
            bl[ni] = *(const h8*)(Bb + 4096 + (wc * 4 + ni) * 512 + lane * 8);
        }
        __builtin_amdgcn_s_setprio(1);
#pragma unroll
        for (int mi = 0; mi < 2; ++mi)
#pragma unroll
            for (int ni = 0; ni < 4; ++ni) {
                acc[mi][ni] = __builtin_amdgcn_mfma_f32_16x16x32_f16(
                    ah[mi], bh[ni], acc[mi][ni], 0, 0, 0);
                acc[mi][ni] = __builtin_amdgcn_mfma_f32_16x16x32_f16(
                    al[mi], bh[ni], acc[mi][ni], 0, 0, 0);
                acc[mi][ni] = __builtin_amdgcn_mfma_f32_16x16x32_f16(
                    ah[mi], bl[ni], acc[mi][ni], 0, 0, 0);
            }
        __builtin_amdgcn_s_setprio(0);
    };

    // ---- prologue ----
    float st0, st1, gv, bt;
    if constexpr (FUSE_BN) {                 // issue these loads FIRST (oldest)
        st0 = stats[half * 512 + tid];
        st1 = stats[half * 512 + 256 + tid];
        gv = g[tid];
        bt = beta[tid];
    }
    loadA(0, 0);
    loadA(1, 1);
    loadA(2, 2);
    stageB(0, 0);
    stageB(1, 1);
    if constexpr (FUSE_BN) {
        const float invN = 1.0f / (float)BATCH;
        float mu = st0 * invN;
        float var = fmaf(-mu, mu, st1 * invN);
        float s = gv * rsqrtf(var + EPS_BN);
        scsh[tid] = s;
        scsh[256 + tid] = fmaf(-mu, s, bt);
        LGKM0();                             // scsh visible before procA
        __builtin_amdgcn_s_barrier();
    }
    procA(0, 0, 0);                          // compiler waits ar[0]'s own loads
    loadA(0, 3);                             // slot 0 freed; tile 3
    VMCNT(6);                                // B(0) done; B(1)+A(3) in flight
    LGKM0();                                 // A[0] ds_writes done
    __builtin_amdgcn_s_barrier();

    // ---- main loop: one raw barrier per tile, counted vmcnt ----
#pragma unroll
    for (int t = 0; t < NT; ++t) {
        if (t + 2 < NT) stageB((t + 2) % 3, t + 2);
        compute(t % 3);
        if (t + 1 < NT) {
            if (t + 3 < NT)      VMCNT(6);   // drain thru B(t+1); A/B(t+2..) fly
            else if (t + 2 < NT) VMCNT(4);
            else                 VMCNT(0);
            __builtin_amdgcn_sched_barrier(0);
            procA((t + 1) % 3, (t + 1) % 3, t + 1);
            if (t + 4 < NT) loadA((t + 4) % 3, t + 4);
        }
        LGKM0();
        __builtin_amdgcn_s_barrier();
    }
    __syncthreads();                         // all waves done -> alias Aring

    // ---- epilogue ----
    float bv[4];
#pragma unroll
    for (int ni = 0; ni < 4; ++ni) bv[ni] = bias[bcol + wc * 64 + ni * 16 + lc];

    if constexpr (EPI == 0) {
        float s[4] = {}, q[4] = {};
#pragma unroll
        for (int mi = 0; mi < 2; ++mi)
#pragma unroll
            for (int j = 0; j < 4; ++j) {
                int gr = brow + wr * 32 + mi * 16 + l4 * 4 + j;
#pragma unroll
                for (int ni = 0; ni < 4; ++ni) {
                    float v = acc[mi][ni][j] + bv[ni];
                    Cout[(size_t)gr * N + bcol + wc * 64 + ni * 16 + lc] = v;
                    s[ni] += v;
                    q[ni] = fmaf(v, v, q[ni]);
                }
            }
#pragma unroll
        for (int ni = 0; ni < 4; ++ni) {
            sR[(wr * 4 + l4) * 128 + wc * 64 + ni * 16 + lc] = s[ni];
            sR[1024 + (wr * 4 + l4) * 128 + wc * 64 + ni * 16 + lc] = q[ni];
        }
        __syncthreads();
        if (tid < 128) {
            float ss = 0.f, qq = 0.f;
#pragma unroll
            for (int i = 0; i < 8; ++i) {
                ss += sR[i * 128 + tid];
                qq += sR[1024 + i * 128 + tid];
            }
            atomicAdd(&red[half * 512 + bcol + tid], ss);
            atomicAdd(&red[half * 512 + 256 + bcol + tid], qq);
        }
    } else {
        float v[2][4][4];                   // [mi][j][ni]
#pragma unroll
        for (int mi = 0; mi < 2; ++mi)
#pragma unroll
            for (int j = 0; j < 4; ++j) {
                float ssq = 0.f;
#pragma unroll
                for (int ni = 0; ni < 4; ++ni) {
                    v[mi][j][ni] = acc[mi][ni][j] + bv[ni];
                    ssq = fmaf(v[mi][j][ni], v[mi][j][ni], ssq);
                }
#pragma unroll
                for (int o = 1; o < 16; o <<= 1) ssq += __shfl_xor(ssq, o);
                if (lc == 0) nLp[(wr * 32 + mi * 16 + l4 * 4 + j) * 2 + wc] = ssq;
            }
        __syncthreads();
        float s[4] = {};
#pragma unroll
        for (int mi = 0; mi < 2; ++mi)
#pragma unroll
            for (int j = 0; j < 4; ++j) {
                int lrow = wr * 32 + mi * 16 + l4 * 4 + j;
                float tot = nLp[lrow * 2] + nLp[lrow * 2 + 1];
                float inv = 1.0f / fmaxf(sqrtf(tot), 1e-12f);
#pragma unroll
                for (int ni = 0; ni < 4; ++ni) {
                    float z = v[mi][j][ni] * inv;
                    Cout[(size_t)(brow + lrow) * DOUT + wc * 64 + ni * 16 + lc] = z;
                    s[ni] += z;
                }
            }
        __syncthreads();
#pragma unroll
        for (int ni = 0; ni < 4; ++ni)
            sR[(wr * 4 + l4) * 128 + wc * 64 + ni * 16 + lc] = s[ni];
        __syncthreads();
        if (tid < 128) {
            float ss = 0.f;
#pragma unroll
            for (int i = 0; i < 8; ++i) ss += sR[i * 128 + tid];
            atomicAdd(&red[tid], ss);
        }
    }
}

// ---------------------------------------------------------------------------
// W prep (hi/lo split, transposed row-major [n][k]) + zeroing block.
// ---------------------------------------------------------------------------
__global__ __launch_bounds__(256) void wprep(
    const float* __restrict__ W1, const float* __restrict__ W2,
    const float* __restrict__ W3,
    _Float16* __restrict__ W1hiT, _Float16* __restrict__ W1loT,
    _Float16* __restrict__ W2hiT, _Float16* __restrict__ W2loT,
    _Float16* __restrict__ W3hiT, _Float16* __restrict__ W3loT,
    float* __restrict__ smalls, float* __restrict__ out)
{
    const int b = blockIdx.x;
    if (b == 56) {
        for (int i = threadIdx.x; i < 2176; i += 256) smalls[i] = 0.f;
        if (threadIdx.x == 0) out[0] = 0.f;
        return;
    }
#pragma unroll
    for (int i = 0; i < 4; ++i) {
        int qd = b * 1024 + i * 256 + threadIdx.x;   // quad index, < 57344
        const float* src; _Float16 *dhi, *dlo; int n, kq, Nw, Kw;
        if (qd < 32768)      { src = W1; dhi = W1hiT; dlo = W1loT;
                               n = qd & 255;            kq = qd >> 8; Nw = 256; Kw = 512; }
        else if (qd < 49152) { src = W2; dhi = W2hiT; dlo = W2loT;
                               n = (qd - 32768) & 255;  kq = (qd - 32768) >> 8; Nw = 256; Kw = 256; }
        else                 { src = W3; dhi = W3hiT; dlo = W3loT;
                               n = (qd - 49152) & 127;  kq = (qd - 49152) >> 7; Nw = 128; Kw = 256; }
        h4 hi, lo;
#pragma unroll
        for (int j = 0; j < 4; ++j) {
            float w = src[(size_t)(kq * 4 + j) * Nw + n];
            _Float16 h = (_Float16)w;
            hi[j] = h;
            lo[j] = (_Float16)(w - (float)h);
        }
        *(h4*)&dhi[(size_t)n * Kw + kq * 4] = hi;
        *(h4*)&dlo[(size_t)n * Kw + kq * 4] = lo;
    }
}

// ---------------------------------------------------------------------------
// Fused positives + loss. 64-lane group handles pair (i, i+B). Grid 512.
// ---------------------------------------------------------------------------
__global__ __launch_bounds__(256) void losspos(const float* __restrict__ reps,
                                               const float* __restrict__ Svec,
                                               float* __restrict__ out)
{
    const int lane = threadIdx.x & 63;
    const int grp = threadIdx.x >> 6;
    __shared__ float part[4];
    float2 sv = ((const float2*)Svec)[lane];
    float acc = 0.f;
#pragma unroll 1
    for (int it = 0; it < 4; ++it) {
        int p = blockIdx.x * 16 + it * 4 + grp;
        float2 a = ((const float2*)(reps + (size_t)p * DOUT))[lane];
        float2 b = ((const float2*)(reps + (size_t)(p + BATCH) * DOUT))[lane];
        float dp  = fmaf(a.x, b.x, a.y * b.y);
        float rsA = fmaf(a.x, sv.x, a.y * sv.y);
        float sdA = fmaf(a.x, a.x, a.y * a.y);
        float rsB = fmaf(b.x, sv.x, b.y * sv.y);
        float sdB = fmaf(b.x, b.x, b.y * b.y);
#pragma unroll
        for (int o = 32; o; o >>= 1) {
            dp  += __shfl_xor(dp, o);
            rsA += __shfl_xor(rsA, o);
            sdA += __shfl_xor(sdA, o);
            rsB += __shfl_xor(rsB, o);
            sdB += __shfl_xor(sdB, o);
        }
        if (lane == 0) {
            float nom = expf(dp / TEMP);
            float dA = (rsA - sdA) / TEMP;
            float dB = (rsB - sdB) / TEMP;
            acc += -logf(nom / dA) - logf(nom / dB);
        }
    }
    if (lane == 0) part[grp] = acc;
    __syncthreads();
    if (threadIdx.x == 0) {
        float t = part[0] + part[1] + part[2] + part[3];
        atomicAdd(out, t * (1.0f / (float)MROWS));
    }
}

extern "C" void kernel_launch(void* const* d_in, const int* in_sizes, int n_in,
                              void* d_out, int out_size, void* d_ws, size_t ws_size,
                              hipStream_t stream)
{
    const float* x1    = (const float*)d_in[0];
    const float* x2    = (const float*)d_in[1];
    const float* W1    = (const float*)d_in[2];
    const float* b1    = (const float*)d_in[3];
    const float* g1    = (const float*)d_in[4];
    const float* beta1 = (const float*)d_in[5];
    const float* W2    = (const float*)d_in[6];
    const float* b2    = (const float*)d_in[7];
    const float* g2    = (const float*)d_in[8];
    const float* beta2 = (const float*)d_in[9];
    const float* W3    = (const float*)d_in[10];
    const float* b3    = (const float*)d_in[11];
    float* out = (float*)d_out;

    // workspace: Y1 @0 (16MB), Y2 @16M (16MB), reps @32M (8MB),
    // W splits @40M (896KB), smalls after.
    char* W = (char*)d_ws;
    float*    Y1   = (float*)(W);
    float*    Y2   = (float*)(W + (16u << 20));
    float*    REPS = (float*)(W + (32u << 20));
    char* wb = W + (40u << 20);
    _Float16* W1HIT = (_Float16*)(wb);
    _Float16* W1LOT = (_Float16*)(wb + 262144);
    _Float16* W2HIT = (_Float16*)(wb + 524288);
    _Float16* W2LOT = (_Float16*)(wb + 655360);
    _Float16* W3HIT = (_Float16*)(wb + 786432);
    _Float16* W3LOT = (_Float16*)(wb + 851968);
    float* smalls   = (float*)  (wb + 917504);
    float* stats1 = smalls;
    float* stats2 = smalls + 1024;
    float* Svec   = smalls + 2048;

    const int big = 1 << 30;

    // W hi/lo transposed splits + zero accumulators/out (57 blocks)
    wprep<<<57, 256, 0, stream>>>(W1, W2, W3, W1HIT, W1LOT, W2HIT, W2LOT,
                                  W3HIT, W3LOT, smalls, out);

    // L1: [x1;x2] @ W1 + b1 -> Y1 (+stats1); X read + f16-split fused
    gemm_fused<DIN, DH, 0, 0><<<512, 256, 0, stream>>>(
        x1, x2, BATCH, W1HIT, W1LOT, nullptr, nullptr, nullptr, b1, Y1, stats1);

    // L2: relu(bn(Y1)) @ W2 + b2 -> Y2 (+stats2); BN+ReLU+split fused
    gemm_fused<DH, DH, 1, 0><<<512, 256, 0, stream>>>(
        Y1, Y1, big, W2HIT, W2LOT, stats1, g1, beta1, b2, Y2, stats2);

    // L3: relu(bn(Y2)) @ W3 + b3 -> row-normalized reps (+Svec)
    gemm_fused<DH, DOUT, 1, 1><<<256, 256, 0, stream>>>(
        Y2, Y2, big, W3HIT, W3LOT, stats2, g2, beta2, b3, REPS, Svec);

    // positives + loss
    losspos<<<512, 256, 0, stream>>>(REPS, Svec, out);
}

// Round 8
// 166.139 us; speedup vs baseline: 1.0174x; 1.0174x over previous
//
#include <hip/hip_runtime.h>
#include <math.h>

// Problem constants (from reference)
#define BATCH   8192
#define MROWS   16384      // 2*BATCH rows processed through the MLP
#define DIN     512
#define DH      256
#define DOUT    128
#define EPS_BN  1e-5f
#define TEMP    0.07f

using f4    = __attribute__((ext_vector_type(4))) float;
using f32x4 = __attribute__((ext_vector_type(4))) float;
using h4    = __attribute__((ext_vector_type(4))) _Float16;
using h8    = __attribute__((ext_vector_type(8))) _Float16;

// async global->LDS, 16B per lane: per-lane GLOBAL src, wave-uniform LDS base
#define GLD_LDS16(gp, lp) __builtin_amdgcn_global_load_lds( \
    (const __attribute__((address_space(1))) void*)(gp),    \
    (__attribute__((address_space(3))) void*)(lp), 16, 0, 0)

#define VMCNT(n) asm volatile("s_waitcnt vmcnt(" #n ")" ::: "memory")
#define LGKM0()  asm volatile("s_waitcnt lgkmcnt(0)" ::: "memory")

// ---------------------------------------------------------------------------
// Round 8: wave-tile 16x128 -> A NEVER goes through LDS.
//   Wave w owns rows w*16..+16 of the 64-row block; its A loads (lane l:
//   row=l&15, k=(l>>4)*8..+8) are EXACTLY the mfma_f32_16x16x32_f16 A-frag
//   layout, so procA (BN-affine+ReLU+hi/lo f16 split) is pure VALU reg->reg.
//   Only B rides LDS (ring-3, global_load_lds, counted vmcnt).  LDS = 50KB
//   -> 3 blocks/CU; launch_bounds(256,3) caps VGPR at 512/3=170.
// Per-iter t: stageB(t+2); compute(t) [16 ds_read_b128 + 24 MFMA];
//   loadA(t+3); VMCNT(8) [drain A(t+1),B(t+1); keep A(t+2),B(t+2),A(t+3)];
//   procA(t+1); s_barrier.  No lgkm wait needed (no A ds_writes).
// EPI=0: C + per-col BN stats.  EPI=1: rownorm + reps + Svec (full row is
//   lane-local-x-16-lane-group now -> single shfl reduce, no cross-wave LDS).
// Grid 1-D: by=wg&255, bx=wg>>8 (col-pair same XCD: 256%8==0 -> A L2 reuse).
// ---------------------------------------------------------------------------
template <int K, int N, int FUSE_BN, int EPI>
__global__ __launch_bounds__(256, 3) void gemm_fused(
    const float* __restrict__ A1, const float* __restrict__ A2, int splitRow,
    const _Float16* __restrict__ BThi, const _Float16* __restrict__ BTlo,
    const float* __restrict__ stats, const float* __restrict__ g,
    const float* __restrict__ beta, const float* __restrict__ bias,
    float* __restrict__ Cout, float* __restrict__ red)
{
    constexpr int NT = K / 32;               // 32-k tiles (16 / 8 / 8)

    const int tid = threadIdx.x;
    const int wave = tid >> 6, lane = tid & 63;
    const int l4 = lane >> 4, lc = lane & 15;
    const int wg = blockIdx.x;
    const int brow = (wg & 255) * 64;
    const int bcol = (wg >> 8) * 128;
    const int half = (brow >= BATCH) ? 1 : 0;

    __shared__ __align__(16) char smem[51200];
    _Float16* Bring = (_Float16*)smem;             // [3][8192] halfs (48KB)
    float*    scsh  = (float*)(smem + 49152);      // sc[256], sh[256] (2KB)
    float*    sR    = (float*)smem;                // epilogue alias [2][16][128]

    // ---- B staging: wave w stages frags {2w,2w+1} of Bhi and Blo ----
    const _Float16* bsrc[4];
    {
        const int co = (bcol + wave * 32 + lc) * K + l4 * 8;
        bsrc[0] = BThi + co;                 // frag 2w   (cols wave*32..+16)
        bsrc[1] = BThi + co + 16 * K;        // frag 2w+1 (cols +16)
        bsrc[2] = BTlo + co;
        bsrc[3] = BTlo + co + 16 * K;
    }
    auto stageB = [&](int buf, int t) {
        _Float16* d = Bring + buf * 8192 + wave * 1024;
        GLD_LDS16(bsrc[0] + t * 32, d);
        GLD_LDS16(bsrc[1] + t * 32, d + 512);
        GLD_LDS16(bsrc[2] + t * 32, d + 4096);
        GLD_LDS16(bsrc[3] + t * 32, d + 4096 + 512);
    };

    // ---- A: pure-register path (frag layout native) ----
    const int growA = brow + wave * 16 + lc;
    const int ak0 = l4 * 8;
    const float* asrc = (growA < splitRow)
        ? (A1 + (size_t)growA * K + ak0)
        : (A2 + (size_t)(growA - splitRow) * K + ak0);

    f4 ar[3][2];                             // 3-deep fp32 A ring (in flight)
    auto loadA = [&](int p, int t) {
        ar[p][0] = *(const f4*)(asrc + t * 32);
        ar[p][1] = *(const f4*)(asrc + t * 32 + 4);
    };
    h8 ah, al;                               // current-tile MFMA A operands
    auto procA = [&](int p, int t) {
        float v[8];
#pragma unroll
        for (int j = 0; j < 4; ++j) { v[j] = ar[p][0][j]; v[4 + j] = ar[p][1][j]; }
        if constexpr (FUSE_BN) {
            f4 s0 = *(const f4*)&scsh[t * 32 + ak0];
            f4 s1 = *(const f4*)&scsh[t * 32 + ak0 + 4];
            f4 h0 = *(const f4*)&scsh[256 + t * 32 + ak0];
            f4 h1 = *(const f4*)&scsh[256 + t * 32 + ak0 + 4];
#pragma unroll
            for (int j = 0; j < 4; ++j) {
                v[j]     = fmaxf(fmaf(v[j],     s0[j], h0[j]), 0.f);
                v[4 + j] = fmaxf(fmaf(v[4 + j], s1[j], h1[j]), 0.f);
            }
        }
#pragma unroll
        for (int j = 0; j < 8; ++j) {
            _Float16 h = (_Float16)v[j];
            ah[j] = h;
            al[j] = (_Float16)(v[j] - (float)h);
        }
    };

    f32x4 acc[8];
#pragma unroll
    for (int ni = 0; ni < 8; ++ni)
#pragma unroll
        for (int c = 0; c < 4; ++c) acc[ni][c] = 0.f;

    auto compute = [&](int buf) {
        const _Float16* Bb = Bring + buf * 8192;
#pragma unroll
        for (int hf = 0; hf < 2; ++hf) {     // two 4-col-group halves: regs low
            h8 bh[4], bl[4];
#pragma unroll
            for (int ni = 0; ni < 4; ++ni) {
                bh[ni] = *(const h8*)(Bb + (hf * 4 + ni) * 512 + lane * 8);
                bl[ni] = *(const h8*)(Bb + 4096 + (hf * 4 + ni) * 512 + lane * 8);
            }
            __builtin_amdgcn_s_setprio(1);
#pragma unroll
            for (int ni = 0; ni < 4; ++ni) {
                acc[hf * 4 + ni] = __builtin_amdgcn_mfma_f32_16x16x32_f16(
                    ah, bh[ni], acc[hf * 4 + ni], 0, 0, 0);
                acc[hf * 4 + ni] = __builtin_amdgcn_mfma_f32_16x16x32_f16(
                    al, bh[ni], acc[hf * 4 + ni], 0, 0, 0);
                acc[hf * 4 + ni] = __builtin_amdgcn_mfma_f32_16x16x32_f16(
                    ah, bl[ni], acc[hf * 4 + ni], 0, 0, 0);
            }
            __builtin_amdgcn_s_setprio(0);
        }
    };

    // ---- prologue.  vmem issue order: [stats] B0 A0 B1 A1 A2 ----
    float st0, st1, gv, bt;
    if constexpr (FUSE_BN) {
        st0 = stats[half * 512 + tid];
        st1 = stats[half * 512 + 256 + tid];
        gv = g[tid];
        bt = beta[tid];
    }
    stageB(0, 0);
    loadA(0, 0);
    stageB(1, 1);
    loadA(1, 1);
    loadA(2, 2);
    if constexpr (FUSE_BN) {
        const float invN = 1.0f / (float)BATCH;
        float mu = st0 * invN;
        float var = fmaf(-mu, mu, st1 * invN);
        float s = gv * rsqrtf(var + EPS_BN);
        scsh[tid] = s;
        scsh[256 + tid] = fmaf(-mu, s, bt);
        LGKM0();                             // scsh visible before procA
        __builtin_amdgcn_s_barrier();
    }
    procA(0, 0);                             // compiler drains B0+A0 (vmcnt 8)
    VMCNT(8);                                // explicit: B0 done for all ours
    __builtin_amdgcn_s_barrier();            // everyone's B0 visible

    // ---- main loop ----
#pragma unroll
    for (int t = 0; t < NT; ++t) {
        if (t + 2 < NT) stageB((t + 2) % 3, t + 2);
        compute(t % 3);
        if (t + 1 < NT) {
            if (t + 3 < NT) loadA((t + 3) % 3, t + 3);
            // FIFO: A(t+1) B(t+1) | A(t+2) B(t+2) A(t+3) -> drain first two
            if (t + 3 < NT)      VMCNT(8);
            else if (t + 2 < NT) VMCNT(6);
            else                 VMCNT(0);
            __builtin_amdgcn_sched_barrier(0);
            procA((t + 1) % 3, t + 1);       // pure VALU -> ah/al
            __builtin_amdgcn_s_barrier();    // B(t+1) visible; WAR for t%3
        }
    }
    __syncthreads();                         // done with Bring -> alias sR

    // ---- epilogue ----
    float bv[8];
#pragma unroll
    for (int ni = 0; ni < 8; ++ni) bv[ni] = bias[bcol + ni * 16 + lc];

    if constexpr (EPI == 0) {
        float s[8] = {}, q[8] = {};
#pragma unroll
        for (int j = 0; j < 4; ++j) {
            int gr = brow + wave * 16 + l4 * 4 + j;
#pragma unroll
            for (int ni = 0; ni < 8; ++ni) {
                float v = acc[ni][j] + bv[ni];
                Cout[(size_t)gr * N + bcol + ni * 16 + lc] = v;
                s[ni] += v;
                q[ni] = fmaf(v, v, q[ni]);
            }
        }
#pragma unroll
        for (int ni = 0; ni < 8; ++ni) {
            sR[(wave * 4 + l4) * 128 + ni * 16 + lc] = s[ni];
            sR[2048 + (wave * 4 + l4) * 128 + ni * 16 + lc] = q[ni];
        }
        __syncthreads();
        if (tid < 128) {
            float ss = 0.f, qq = 0.f;
#pragma unroll
            for (int i = 0; i < 16; ++i) {
                ss += sR[i * 128 + tid];
                qq += sR[2048 + i * 128 + tid];
            }
            atomicAdd(&red[half * 512 + bcol + tid], ss);
            atomicAdd(&red[half * 512 + 256 + bcol + tid], qq);
        }
    } else {
        // N==128: full row = 8 ni x 16-lane group -> single shfl reduce
        float s[8] = {};
#pragma unroll
        for (int j = 0; j < 4; ++j) {
            float vj[8];
            float ssq = 0.f;
#pragma unroll
            for (int ni = 0; ni < 8; ++ni) {
                vj[ni] = acc[ni][j] + bv[ni];
                ssq = fmaf(vj[ni], vj[ni], ssq);
            }
#pragma unroll
            for (int o = 1; o < 16; o <<= 1) ssq += __shfl_xor(ssq, o);
            float inv = 1.0f / fmaxf(sqrtf(ssq), 1e-12f);
            int gr = brow + wave * 16 + l4 * 4 + j;
#pragma unroll
            for (int ni = 0; ni < 8; ++ni) {
                float z = vj[ni] * inv;
                Cout[(size_t)gr * DOUT + ni * 16 + lc] = z;
                s[ni] += z;
            }
        }
#pragma unroll
        for (int ni = 0; ni < 8; ++ni)
            sR[(wave * 4 + l4) * 128 + ni * 16 + lc] = s[ni];
        __syncthreads();
        if (tid < 128) {
            float ss = 0.f;
#pragma unroll
            for (int i = 0; i < 16; ++i) ss += sR[i * 128 + tid];
            atomicAdd(&red[tid], ss);
        }
    }
}

// ---------------------------------------------------------------------------
// W prep via LDS 64x64 transpose: coalesced fp32 reads AND contiguous h4
// writes (round-7 version wrote 8B at 1KB stride -> write-amplified).
// Blocks: W1 = 32 (8 kb x 4 nb), W2 = 16, W3 = 8, zero-block = 1. Grid 57.
// ---------------------------------------------------------------------------
__global__ __launch_bounds__(256) void wprep(
    const float* __restrict__ W1, const float* __restrict__ W2,
    const float* __restrict__ W3,
    _Float16* __restrict__ W1hiT, _Float16* __restrict__ W1loT,
    _Float16* __restrict__ W2hiT, _Float16* __restrict__ W2loT,
    _Float16* __restrict__ W3hiT, _Float16* __restrict__ W3loT,
    float* __restrict__ smalls, float* __restrict__ out)
{
    const int b = blockIdx.x;
    if (b == 56) {
        for (int i = threadIdx.x; i < 2176; i += 256) smalls[i] = 0.f;
        if (threadIdx.x == 0) out[0] = 0.f;
        return;
    }
    const float* src; _Float16 *dhi, *dlo; int Nw, Kw, kb, nb;
    if (b < 32)      { src = W1; dhi = W1hiT; dlo = W1loT; Nw = 256; Kw = 512;
                       kb = b >> 2; nb = b & 3; }
    else if (b < 48) { int r = b - 32; src = W2; dhi = W2hiT; dlo = W2loT;
                       Nw = 256; Kw = 256; kb = r >> 2; nb = r & 3; }
    else             { int r = b - 48; src = W3; dhi = W3hiT; dlo = W3loT;
                       Nw = 128; Kw = 256; kb = r >> 1; nb = r & 1; }

    __shared__ float tile[64][65];
    const int tx = threadIdx.x & 15, ty = threadIdx.x >> 4;
#pragma unroll
    for (int it = 0; it < 4; ++it) {         // read [k][n], coalesced n
        int kk = it * 16 + ty;
        f4 v = *(const f4*)&src[(size_t)(kb * 64 + kk) * Nw + nb * 64 + tx * 4];
#pragma unroll
        for (int j = 0; j < 4; ++j) tile[kk][tx * 4 + j] = v[j];
    }
    __syncthreads();
#pragma unroll
    for (int it = 0; it < 4; ++it) {         // write [n][k], contiguous k
        int n = it * 16 + ty;
        h4 hi, lo;
#pragma unroll
        for (int j = 0; j < 4; ++j) {
            float w = tile[tx * 4 + j][n];
            _Float16 h = (_Float16)w;
            hi[j] = h;
            lo[j] = (_Float16)(w - (float)h);
        }
        size_t o = (size_t)(nb * 64 + n) * Kw + kb * 64 + tx * 4;
        *(h4*)&dhi[o] = hi;
        *(h4*)&dlo[o] = lo;
    }
}

// ---------------------------------------------------------------------------
// Fused positives + loss. 64-lane group handles pair (i, i+B). Grid 512.
// ---------------------------------------------------------------------------
__global__ __launch_bounds__(256) void losspos(const float* __restrict__ reps,
                                               const float* __restrict__ Svec,
                                               float* __restrict__ out)
{
    const int lane = threadIdx.x & 63;
    const int grp = threadIdx.x >> 6;
    __shared__ float part[4];
    float2 sv = ((const float2*)Svec)[lane];
    float acc = 0.f;
#pragma unroll 1
    for (int it = 0; it < 4; ++it) {
        int p = blockIdx.x * 16 + it * 4 + grp;
        float2 a = ((const float2*)(reps + (size_t)p * DOUT))[lane];
        float2 b = ((const float2*)(reps + (size_t)(p + BATCH) * DOUT))[lane];
        float dp  = fmaf(a.x, b.x, a.y * b.y);
        float rsA = fmaf(a.x, sv.x, a.y * sv.y);
        float sdA = fmaf(a.x, a.x, a.y * a.y);
        float rsB = fmaf(b.x, sv.x, b.y * sv.y);
        float sdB = fmaf(b.x, b.x, b.y * b.y);
#pragma unroll
        for (int o = 32; o; o >>= 1) {
            dp  += __shfl_xor(dp, o);
            rsA += __shfl_xor(rsA, o);
            sdA += __shfl_xor(sdA, o);
            rsB += __shfl_xor(rsB, o);
            sdB += __shfl_xor(sdB, o);
        }
        if (lane == 0) {
            float nom = expf(dp / TEMP);
            float dA = (rsA - sdA) / TEMP;
            float dB = (rsB - sdB) / TEMP;
            acc += -logf(nom / dA) - logf(nom / dB);
        }
    }
    if (lane == 0) part[grp] = acc;
    __syncthreads();
    if (threadIdx.x == 0) {
        float t = part[0] + part[1] + part[2] + part[3];
        atomicAdd(out, t * (1.0f / (float)MROWS));
    }
}

extern "C" void kernel_launch(void* const* d_in, const int* in_sizes, int n_in,
                              void* d_out, int out_size, void* d_ws, size_t ws_size,
                              hipStream_t stream)
{
    const float* x1    = (const float*)d_in[0];
    const float* x2    = (const float*)d_in[1];
    const float* W1    = (const float*)d_in[2];
    const float* b1    = (const float*)d_in[3];
    const float* g1    = (const float*)d_in[4];
    const float* beta1 = (const float*)d_in[5];
    const float* W2    = (const float*)d_in[6];
    const float* b2    = (const float*)d_in[7];
    const float* g2    = (const float*)d_in[8];
    const float* beta2 = (const float*)d_in[9];
    const float* W3    = (const float*)d_in[10];
    const float* b3    = (const float*)d_in[11];
    float* out = (float*)d_out;

    // workspace: Y1 @0 (16MB), Y2 @16M (16MB), reps @32M (8MB),
    // W splits @40M (896KB), smalls after.
    char* W = (char*)d_ws;
    float*    Y1   = (float*)(W);
    float*    Y2   = (float*)(W + (16u << 20));
    float*    REPS = (float*)(W + (32u << 20));
    char* wb = W + (40u << 20);
    _Float16* W1HIT = (_Float16*)(wb);
    _Float16* W1LOT = (_Float16*)(wb + 262144);
    _Float16* W2HIT = (_Float16*)(wb + 524288);
    _Float16* W2LOT = (_Float16*)(wb + 655360);
    _Float16* W3HIT = (_Float16*)(wb + 786432);
    _Float16* W3LOT = (_Float16*)(wb + 851968);
    float* smalls   = (float*)  (wb + 917504);
    float* stats1 = smalls;
    float* stats2 = smalls + 1024;
    float* Svec   = smalls + 2048;

    const int big = 1 << 30;

    // W hi/lo transposed splits (LDS transpose) + zeroing (57 blocks)
    wprep<<<57, 256, 0, stream>>>(W1, W2, W3, W1HIT, W1LOT, W2HIT, W2LOT,
                                  W3HIT, W3LOT, smalls, out);

    // L1: [x1;x2] @ W1 + b1 -> Y1 (+stats1)
    gemm_fused<DIN, DH, 0, 0><<<512, 256, 0, stream>>>(
        x1, x2, BATCH, W1HIT, W1LOT, nullptr, nullptr, nullptr, b1, Y1, stats1);

    // L2: relu(bn(Y1)) @ W2 + b2 -> Y2 (+stats2)
    gemm_fused<DH, DH, 1, 0><<<512, 256, 0, stream>>>(
        Y1, Y1, big, W2HIT, W2LOT, stats1, g1, beta1, b2, Y2, stats2);

    // L3: relu(bn(Y2)) @ W3 + b3 -> row-normalized reps (+Svec)
    gemm_fused<DH, DOUT, 1, 1><<<256, 256, 0, stream>>>(
        Y2, Y2, big, W3HIT, W3LOT, stats2, g2, beta2, b3, REPS, Svec);

    // positives + loss
    losspos<<<512, 256, 0, stream>>>(REPS, Svec, out);
}